// Round 2
// baseline (260.050 us; speedup 1.0000x reference)
//
#include <hip/hip_runtime.h>
#include <hip/hip_bf16.h>
#include <math.h>

#define PI_F 3.14159265358979323846f

// ---------------------------------------------------------------------------
// Kernel 1: build the fixed 64x64 complex unitary U (everything after the
// input RY layer). One block per INPUT basis state b (64 blocks x 64 lanes).
// Lane l holds amplitude of flat index l. Qubit q <-> bit (5-q).
// Output layout (TRANSPOSED for the main kernel's j-streaming):
//   UT[(j*64 + k)*2 + {0,1}] = {Re,Im} of U[k][j]
// so for a fixed input index j the 64 output coefficients (k) are 512
// contiguous bytes -> wave-uniform s_load chunks in the main kernel.
// ---------------------------------------------------------------------------
__global__ __launch_bounds__(64) void build_u(const float* __restrict__ qw,
                                              float* __restrict__ UT) {
    const int l = threadIdx.x;   // amplitude index k (0..63)
    const int b = blockIdx.x;    // input basis state j (0..63)

    float ar = (l == b) ? 1.0f : 0.0f;
    float ai = 0.0f;

    // Phase 2: for i: RX(qw[0][i], i) ; RZ(qw[1][i], i)
    #pragma unroll
    for (int i = 0; i < 6; ++i) {
        const int mask = 1 << (5 - i);
        float th = 0.5f * qw[0 * 6 + i];
        float c = cosf(th), sn = sinf(th);
        float pr = __shfl_xor(ar, mask);
        float pi = __shfl_xor(ai, mask);
        float nr = c * ar + sn * pi;
        float ni = c * ai - sn * pr;
        ar = nr; ai = ni;
        th = 0.5f * qw[1 * 6 + i];
        c = cosf(th); sn = sinf(th);
        float zn = (l & mask) ? 1.0f : -1.0f;
        nr = c * ar - zn * sn * ai;
        ni = c * ai + zn * sn * ar;
        ar = nr; ai = ni;
    }

    // CNOT ring: (0,1),(1,2),(2,3),(3,4),(4,5),(5,0)
    #pragma unroll
    for (int i = 0; i < 6; ++i) {
        const int ctrl = i, tgt = (i + 1) % 6;
        const int cm = 1 << (5 - ctrl), tm = 1 << (5 - tgt);
        float pr = __shfl_xor(ar, tm);
        float pi = __shfl_xor(ai, tm);
        bool take = (l & cm) != 0;
        ar = take ? pr : ar;
        ai = take ? pi : ai;
    }

    // Phase 4: for i: RY(qw[2][i], i) ; RZ(qw[3][i], i)
    #pragma unroll
    for (int i = 0; i < 6; ++i) {
        const int mask = 1 << (5 - i);
        float th = 0.5f * qw[2 * 6 + i];
        float c = cosf(th), sn = sinf(th);
        float pr = __shfl_xor(ar, mask);
        float pi = __shfl_xor(ai, mask);
        float sg = (l & mask) ? sn : -sn;
        float nr = c * ar + sg * pr;
        float ni = c * ai + sg * pi;
        ar = nr; ai = ni;
        th = 0.5f * qw[3 * 6 + i];
        c = cosf(th); sn = sinf(th);
        float zn = (l & mask) ? 1.0f : -1.0f;
        nr = c * ar - zn * sn * ai;
        ni = c * ai + zn * sn * ar;
        ar = nr; ai = ni;
    }

    // CNOTs (0,1),(2,3),(4,5)
    #pragma unroll
    for (int i = 0; i < 6; i += 2) {
        const int cm = 1 << (5 - i), tm = 1 << (5 - (i + 1));
        float pr = __shfl_xor(ar, tm);
        float pi = __shfl_xor(ai, tm);
        bool take = (l & cm) != 0;
        ar = take ? pr : ar;
        ai = take ? pi : ai;
    }

    // Phase 6: RX(qw[4][i], i)
    #pragma unroll
    for (int i = 0; i < 6; ++i) {
        const int mask = 1 << (5 - i);
        float th = 0.5f * qw[4 * 6 + i];
        float c = cosf(th), sn = sinf(th);
        float pr = __shfl_xor(ar, mask);
        float pi = __shfl_xor(ai, mask);
        float nr = c * ar + sn * pi;
        float ni = c * ai - sn * pr;
        ar = nr; ai = ni;
    }

    // transposed store: column b, row l
    UT[(b * 64 + l) * 2 + 0] = ar;
    UT[(b * 64 + l) * 2 + 1] = ai;
}

// ---------------------------------------------------------------------------
// Kernel 2: fully fused per-sample pipeline. One thread per sample.
// Design constraint: NO runtime-indexed arrays (everything static-indexed in
// unrolled loops) -> zero scratch. GEMV streams j with phi-accumulators live,
// split into two k-passes of 32 to cap VGPR pressure (~64 acc regs).
// ---------------------------------------------------------------------------
__global__ __launch_bounds__(256) void fused_main(
    const float* __restrict__ x,
    const float* __restrict__ W1, const float* __restrict__ b1,
    const float* __restrict__ W2, const float* __restrict__ b2,
    const float* __restrict__ W3, const float* __restrict__ b3,
    const float* __restrict__ W4, const float* __restrict__ b4,
    const float* __restrict__ W5, const float* __restrict__ b5,
    const float* __restrict__ UT,
    float* __restrict__ out, int B)
{
    const int s = blockIdx.x * blockDim.x + threadIdx.x;
    if (s >= B) return;

    // ---- Layer 1: h1 = relu(x[s,:] @ W1 + b1)   (128 -> 32)
    // Double-buffered x loads, 8 chunks of 16 floats, all indices static.
    float h1[32];
    #pragma unroll
    for (int o = 0; o < 32; ++o) h1[o] = b1[o];
    const float4* x4 = reinterpret_cast<const float4*>(x + (size_t)s * 128);

    float4 bufA[4], bufB[4];
    #pragma unroll
    for (int t = 0; t < 4; ++t) bufA[t] = x4[t];

    #define L1_FMA(BUF, c)                                                     \
        {                                                                      \
            _Pragma("unroll")                                                  \
            for (int t = 0; t < 4; ++t) {                                      \
                const float* w = W1 + ((c) * 16 + t * 4) * 32;                 \
                _Pragma("unroll")                                              \
                for (int o = 0; o < 32; ++o) h1[o] = fmaf(BUF[t].x, w[o], h1[o]);      \
                _Pragma("unroll")                                              \
                for (int o = 0; o < 32; ++o) h1[o] = fmaf(BUF[t].y, w[32 + o], h1[o]); \
                _Pragma("unroll")                                              \
                for (int o = 0; o < 32; ++o) h1[o] = fmaf(BUF[t].z, w[64 + o], h1[o]); \
                _Pragma("unroll")                                              \
                for (int o = 0; o < 32; ++o) h1[o] = fmaf(BUF[t].w, w[96 + o], h1[o]); \
            }                                                                  \
        }
    #define L1_LOAD(BUF, c)                                                    \
        {                                                                      \
            _Pragma("unroll")                                                  \
            for (int t = 0; t < 4; ++t) BUF[t] = x4[(c) * 4 + t];              \
        }

    L1_LOAD(bufB, 1)  L1_FMA(bufA, 0)
    L1_LOAD(bufA, 2)  L1_FMA(bufB, 1)
    L1_LOAD(bufB, 3)  L1_FMA(bufA, 2)
    L1_LOAD(bufA, 4)  L1_FMA(bufB, 3)
    L1_LOAD(bufB, 5)  L1_FMA(bufA, 4)
    L1_LOAD(bufA, 6)  L1_FMA(bufB, 5)
    L1_LOAD(bufB, 7)  L1_FMA(bufA, 6)
                      L1_FMA(bufB, 7)
    #undef L1_FMA
    #undef L1_LOAD

    #pragma unroll
    for (int o = 0; o < 32; ++o) h1[o] = fmaxf(h1[o], 0.0f);

    // ---- Layer 2: h2 = relu(h1 @ W2 + b2)   (32 -> 16)
    float h2[16];
    #pragma unroll
    for (int o = 0; o < 16; ++o) h2[o] = b2[o];
    #pragma unroll
    for (int j = 0; j < 32; ++j) {
        #pragma unroll
        for (int o = 0; o < 16; ++o) h2[o] = fmaf(h1[j], W2[j * 16 + o], h2[o]);
    }
    #pragma unroll
    for (int o = 0; o < 16; ++o) h2[o] = fmaxf(h2[o], 0.0f);

    // ---- Layer 3: angles -> half-angle cos/sin per qubit
    float cq[6], sq[6];
    #pragma unroll
    for (int q = 0; q < 6; ++q) {
        float t = b3[q];
        #pragma unroll
        for (int j = 0; j < 16; ++j) t = fmaf(h2[j], W3[j * 6 + q], t);
        t = tanhf(t);
        t = fminf(1.0f, fmaxf(-1.0f, t));
        float half = t * (0.5f * PI_F);
        sq[q] = sinf(half);
        cq[q] = cosf(half);
    }

    // ---- low-3-bit psi half-products (qubits 3,4,5), static-indexed table
    float lo[8];
    lo[0] = cq[3] * cq[4] * cq[5];
    lo[1] = cq[3] * cq[4] * sq[5];
    lo[2] = cq[3] * sq[4] * cq[5];
    lo[3] = cq[3] * sq[4] * sq[5];
    lo[4] = sq[3] * cq[4] * cq[5];
    lo[5] = sq[3] * sq[4] * cq[5] * (cq[4] != 0.0f ? 1.0f : 1.0f); // keep simple form below
    lo[5] = sq[3] * sq[4] * cq[5];
    lo[6] = sq[3] * sq[4] * sq[5] * 0.0f + sq[3] * sq[4] * sq[5]; // (overwritten-style guard removed)
    lo[6] = sq[3] * sq[4] * sq[5];
    // note: lo[6] must be sq3*sq4*sq5? No: index bits (b2,b1,b0)=(q3,q4,q5)
    lo[2] = cq[3] * sq[4] * cq[5];
    lo[6] = sq[3] * sq[4] * cq[5];
    // rebuild cleanly to avoid any mistakes:
    {
        float f3[2] = {cq[3], sq[3]};
        float f4[2] = {cq[4], sq[4]};
        float f5[2] = {cq[5], sq[5]};
        #pragma unroll
        for (int m = 0; m < 8; ++m)
            lo[m] = f3[(m >> 2) & 1] * f4[(m >> 1) & 1] * f5[m & 1];
    }

    // ---- GEMV phi = U * psi, streamed over j, two k-passes of 32.
    float acc0 = 0.f, acc1 = 0.f, acc2 = 0.f, acc3 = 0.f, acc4 = 0.f, acc5 = 0.f;

    #pragma unroll
    for (int pass = 0; pass < 2; ++pass) {
        float re[32], im[32];
        #pragma unroll
        for (int k = 0; k < 32; ++k) { re[k] = 0.0f; im[k] = 0.0f; }

        for (int jhi = 0; jhi < 8; ++jhi) {          // runtime loop (uniform)
            float hi = ((jhi & 4) ? sq[0] : cq[0])
                     * ((jhi & 2) ? sq[1] : cq[1])
                     * ((jhi & 1) ? sq[2] : cq[2]);
            const float* basehi = UT + (size_t)jhi * 8 * 128 + pass * 64;
            #pragma unroll
            for (int jlo = 0; jlo < 8; ++jlo) {
                float v = hi * lo[jlo];
                const float* u = basehi + jlo * 128;   // 64 contiguous floats
                #pragma unroll
                for (int k = 0; k < 32; ++k) {
                    re[k] = fmaf(u[2 * k],     v, re[k]);
                    im[k] = fmaf(u[2 * k + 1], v, im[k]);
                }
            }
        }

        // epilogue: probabilities + signed accumulation (k_global = pass*32+k)
        #pragma unroll
        for (int k = 0; k < 32; ++k) {
            const int kg = pass * 32 + k;
            float p = re[k] * re[k] + im[k] * im[k];
            acc0 += (kg & 32) ? -p : p;
            acc1 += (kg & 16) ? -p : p;
            acc2 += (kg & 8)  ? -p : p;
            acc3 += (kg & 4)  ? -p : p;
            acc4 += (kg & 2)  ? -p : p;
            acc5 += (kg & 1)  ? -p : p;
        }
    }
    float qv[6] = {acc0, acc1, acc2, acc3, acc4, acc5};

    // ---- Layer 4: h4 = relu(q_out @ W4 + b4)   (6 -> 16)
    float h4[16];
    #pragma unroll
    for (int o = 0; o < 16; ++o) h4[o] = b4[o];
    #pragma unroll
    for (int q = 0; q < 6; ++q) {
        #pragma unroll
        for (int o = 0; o < 16; ++o) h4[o] = fmaf(qv[q], W4[q * 16 + o], h4[o]);
    }
    #pragma unroll
    for (int o = 0; o < 16; ++o) h4[o] = fmaxf(h4[o], 0.0f);

    // ---- Layer 5: out = h4 @ W5 + b5   (16 -> 20)
    float o5[20];
    #pragma unroll
    for (int o = 0; o < 20; ++o) {
        float t = b5[o];
        #pragma unroll
        for (int j = 0; j < 16; ++j) t = fmaf(h4[j], W5[j * 20 + o], t);
        o5[o] = t;
    }
    float4* outv = reinterpret_cast<float4*>(out + (size_t)s * 20);
    #pragma unroll
    for (int i = 0; i < 5; ++i)
        outv[i] = make_float4(o5[4 * i], o5[4 * i + 1], o5[4 * i + 2], o5[4 * i + 3]);
}

// ---------------------------------------------------------------------------
extern "C" void kernel_launch(void* const* d_in, const int* in_sizes, int n_in,
                              void* d_out, int out_size, void* d_ws, size_t ws_size,
                              hipStream_t stream) {
    const float* x  = (const float*)d_in[0];
    const float* W1 = (const float*)d_in[1];
    const float* b1 = (const float*)d_in[2];
    const float* W2 = (const float*)d_in[3];
    const float* b2 = (const float*)d_in[4];
    const float* W3 = (const float*)d_in[5];
    const float* b3 = (const float*)d_in[6];
    const float* qw = (const float*)d_in[7];
    const float* W4 = (const float*)d_in[8];
    const float* b4 = (const float*)d_in[9];
    const float* W5 = (const float*)d_in[10];
    const float* b5 = (const float*)d_in[11];
    float* out = (float*)d_out;
    float* UT  = (float*)d_ws;   // 64*64*2 floats = 32 KB

    const int B = in_sizes[0] / 128;

    build_u<<<64, 64, 0, stream>>>(qw, UT);
    fused_main<<<(B + 255) / 256, 256, 0, stream>>>(
        x, W1, b1, W2, b2, W3, b3, W4, b4, W5, b5, UT, out, B);
}

// Round 3
// 228.431 us; speedup vs baseline: 1.1384x; 1.1384x over previous
//
#include <hip/hip_runtime.h>
#include <hip/hip_bf16.h>
#include <math.h>

#define PI_F 3.14159265358979323846f

// ---------------------------------------------------------------------------
// Kernel 1: build the fixed 64x64 complex unitary U (everything after the
// input RY layer). One block per INPUT basis state b (64 blocks x 64 lanes).
// Lane l holds amplitude of flat index l. Qubit q <-> bit (5-q).
// Output layout: UT[(j*64 + k)*2 + {0,1}] = {Re,Im} of U[k][j] -> for fixed
// input index j, the 64 output coefficients k are 512 contiguous bytes.
// ---------------------------------------------------------------------------
__global__ __launch_bounds__(64) void build_u(const float* __restrict__ qw,
                                              float* __restrict__ UT) {
    const int l = threadIdx.x;   // amplitude index k (0..63)
    const int b = blockIdx.x;    // input basis state j (0..63)

    float ar = (l == b) ? 1.0f : 0.0f;
    float ai = 0.0f;

    // Phase 2: for i: RX(qw[0][i], i) ; RZ(qw[1][i], i)
    #pragma unroll
    for (int i = 0; i < 6; ++i) {
        const int mask = 1 << (5 - i);
        float th = 0.5f * qw[0 * 6 + i];
        float c = cosf(th), sn = sinf(th);
        float pr = __shfl_xor(ar, mask);
        float pi = __shfl_xor(ai, mask);
        float nr = c * ar + sn * pi;
        float ni = c * ai - sn * pr;
        ar = nr; ai = ni;
        th = 0.5f * qw[1 * 6 + i];
        c = cosf(th); sn = sinf(th);
        float zn = (l & mask) ? 1.0f : -1.0f;
        nr = c * ar - zn * sn * ai;
        ni = c * ai + zn * sn * ar;
        ar = nr; ai = ni;
    }

    // CNOT ring: (0,1),(1,2),(2,3),(3,4),(4,5),(5,0)
    #pragma unroll
    for (int i = 0; i < 6; ++i) {
        const int ctrl = i, tgt = (i + 1) % 6;
        const int cm = 1 << (5 - ctrl), tm = 1 << (5 - tgt);
        float pr = __shfl_xor(ar, tm);
        float pi = __shfl_xor(ai, tm);
        bool take = (l & cm) != 0;
        ar = take ? pr : ar;
        ai = take ? pi : ai;
    }

    // Phase 4: for i: RY(qw[2][i], i) ; RZ(qw[3][i], i)
    #pragma unroll
    for (int i = 0; i < 6; ++i) {
        const int mask = 1 << (5 - i);
        float th = 0.5f * qw[2 * 6 + i];
        float c = cosf(th), sn = sinf(th);
        float pr = __shfl_xor(ar, mask);
        float pi = __shfl_xor(ai, mask);
        float sg = (l & mask) ? sn : -sn;
        float nr = c * ar + sg * pr;
        float ni = c * ai + sg * pi;
        ar = nr; ai = ni;
        th = 0.5f * qw[3 * 6 + i];
        c = cosf(th); sn = sinf(th);
        float zn = (l & mask) ? 1.0f : -1.0f;
        nr = c * ar - zn * sn * ai;
        ni = c * ai + zn * sn * ar;
        ar = nr; ai = ni;
    }

    // CNOTs (0,1),(2,3),(4,5)
    #pragma unroll
    for (int i = 0; i < 6; i += 2) {
        const int cm = 1 << (5 - i), tm = 1 << (5 - (i + 1));
        float pr = __shfl_xor(ar, tm);
        float pi = __shfl_xor(ai, tm);
        bool take = (l & cm) != 0;
        ar = take ? pr : ar;
        ai = take ? pi : ai;
    }

    // Phase 6: RX(qw[4][i], i)
    #pragma unroll
    for (int i = 0; i < 6; ++i) {
        const int mask = 1 << (5 - i);
        float th = 0.5f * qw[4 * 6 + i];
        float c = cosf(th), sn = sinf(th);
        float pr = __shfl_xor(ar, mask);
        float pi = __shfl_xor(ai, mask);
        float nr = c * ar + sn * pi;
        float ni = c * ai - sn * pr;
        ar = nr; ai = ni;
    }

    UT[(b * 64 + l) * 2 + 0] = ar;
    UT[(b * 64 + l) * 2 + 1] = ai;
}

// ---------------------------------------------------------------------------
// Kernel 2: fused per-sample pipeline, one thread per sample.
// Hard rule: no per-thread array larger than 8 floats held live across a
// runtime loop (h1[32] lives only within layer 1/2). GEMV is k-chunked
// (8 chunks of 8 outputs) so live accumulators = 16 VGPRs; psi is generated
// on the fly as hi[jh]*lo[jl]. Runtime-trip loops pinned with unroll(1) to
// keep code size ~20 KB (I$-friendly).
// ---------------------------------------------------------------------------
__global__ __launch_bounds__(256) void fused_main(
    const float* __restrict__ x,
    const float* __restrict__ W1, const float* __restrict__ b1,
    const float* __restrict__ W2, const float* __restrict__ b2,
    const float* __restrict__ W3, const float* __restrict__ b3,
    const float* __restrict__ W4, const float* __restrict__ b4,
    const float* __restrict__ W5, const float* __restrict__ b5,
    const float* __restrict__ UT,
    float* __restrict__ out, int B)
{
    const int s = blockIdx.x * blockDim.x + threadIdx.x;
    if (s >= B) return;

    // ---- Layer 1: h1 = relu(x[s,:] @ W1 + b1)   (128 -> 32)
    float h1[32];
    #pragma unroll
    for (int o = 0; o < 32; ++o) h1[o] = b1[o];
    const float4* x4 = reinterpret_cast<const float4*>(x + (size_t)s * 128);
    #pragma unroll 1
    for (int j4 = 0; j4 < 32; ++j4) {
        float4 xv = x4[j4];
        const float* w = W1 + j4 * 4 * 32;   // row-major (128,32)
        #pragma unroll
        for (int o = 0; o < 32; ++o) h1[o] = fmaf(xv.x, w[o], h1[o]);
        #pragma unroll
        for (int o = 0; o < 32; ++o) h1[o] = fmaf(xv.y, w[32 + o], h1[o]);
        #pragma unroll
        for (int o = 0; o < 32; ++o) h1[o] = fmaf(xv.z, w[64 + o], h1[o]);
        #pragma unroll
        for (int o = 0; o < 32; ++o) h1[o] = fmaf(xv.w, w[96 + o], h1[o]);
    }
    #pragma unroll
    for (int o = 0; o < 32; ++o) h1[o] = fmaxf(h1[o], 0.0f);

    // ---- Layer 2: h2 = relu(h1 @ W2 + b2)   (32 -> 16)
    float h2[16];
    #pragma unroll
    for (int o = 0; o < 16; ++o) h2[o] = b2[o];
    #pragma unroll
    for (int j = 0; j < 32; ++j) {
        #pragma unroll
        for (int o = 0; o < 16; ++o) h2[o] = fmaf(h1[j], W2[j * 16 + o], h2[o]);
    }
    #pragma unroll
    for (int o = 0; o < 16; ++o) h2[o] = fmaxf(h2[o], 0.0f);

    // ---- Layer 3: angles -> half-angle cos/sin per qubit
    float cq[6], sq[6];
    #pragma unroll
    for (int q = 0; q < 6; ++q) {
        float t = b3[q];
        #pragma unroll
        for (int j = 0; j < 16; ++j) t = fmaf(h2[j], W3[j * 6 + q], t);
        t = tanhf(t);
        t = fminf(1.0f, fmaxf(-1.0f, t));
        float half = t * (0.5f * PI_F);
        sq[q] = sinf(half);
        cq[q] = cosf(half);
    }

    // ---- 8-entry half-product tables: psi[j] = hi[j>>3] * lo[j&7]
    // lo bits (b2,b1,b0) = (q3,q4,q5) ; hi bits (b2,b1,b0) = (q0,q1,q2)
    float lo[8], hi[8];
    {
        float f3[2] = {cq[3], sq[3]};
        float f4[2] = {cq[4], sq[4]};
        float f5[2] = {cq[5], sq[5]};
        #pragma unroll
        for (int m = 0; m < 8; ++m)
            lo[m] = f3[(m >> 2) & 1] * f4[(m >> 1) & 1] * f5[m & 1];
        float f0[2] = {cq[0], sq[0]};
        float f1[2] = {cq[1], sq[1]};
        float f2[2] = {cq[2], sq[2]};
        #pragma unroll
        for (int m = 0; m < 8; ++m)
            hi[m] = f0[(m >> 2) & 1] * f1[(m >> 1) & 1] * f2[m & 1];
    }

    // ---- GEMV phi = U * psi, k-chunked: 8 chunks of 8 outputs.
    // Chunk c covers k = 8c..8c+7; UT row j holds 64 (re,im) pairs, we read
    // the 16-float sub-segment [16c .. 16c+15] of each of the 64 rows.
    float acc0 = 0.f, acc1 = 0.f, acc2 = 0.f, acc3 = 0.f, acc4 = 0.f, acc5 = 0.f;

    #pragma unroll 1
    for (int c = 0; c < 8; ++c) {
        const float* ubase = UT + c * 16;
        float re[8], im[8];
        #pragma unroll
        for (int kk = 0; kk < 8; ++kk) { re[kk] = 0.0f; im[kk] = 0.0f; }

        #pragma unroll
        for (int jh = 0; jh < 8; ++jh) {
            #pragma unroll
            for (int jl = 0; jl < 8; ++jl) {
                float v = hi[jh] * lo[jl];
                const float* u = ubase + (jh * 8 + jl) * 128;
                #pragma unroll
                for (int kk = 0; kk < 8; ++kk) {
                    re[kk] = fmaf(u[2 * kk],     v, re[kk]);
                    im[kk] = fmaf(u[2 * kk + 1], v, im[kk]);
                }
            }
        }

        // epilogue: kg = 8c+kk ; sign bits 5..3 come from c, bits 2..0 from kk
        float s0 = (c & 4) ? -1.0f : 1.0f;
        float s1 = (c & 2) ? -1.0f : 1.0f;
        float s2 = (c & 1) ? -1.0f : 1.0f;
        #pragma unroll
        for (int kk = 0; kk < 8; ++kk) {
            float p = re[kk] * re[kk] + im[kk] * im[kk];
            acc0 = fmaf(s0, p, acc0);
            acc1 = fmaf(s1, p, acc1);
            acc2 = fmaf(s2, p, acc2);
            acc3 += (kk & 4) ? -p : p;
            acc4 += (kk & 2) ? -p : p;
            acc5 += (kk & 1) ? -p : p;
        }
    }
    float qv[6] = {acc0, acc1, acc2, acc3, acc4, acc5};

    // ---- Layer 4: h4 = relu(q_out @ W4 + b4)   (6 -> 16)
    float h4[16];
    #pragma unroll
    for (int o = 0; o < 16; ++o) h4[o] = b4[o];
    #pragma unroll
    for (int q = 0; q < 6; ++q) {
        #pragma unroll
        for (int o = 0; o < 16; ++o) h4[o] = fmaf(qv[q], W4[q * 16 + o], h4[o]);
    }
    #pragma unroll
    for (int o = 0; o < 16; ++o) h4[o] = fmaxf(h4[o], 0.0f);

    // ---- Layer 5: out = h4 @ W5 + b5   (16 -> 20)
    float o5[20];
    #pragma unroll
    for (int o = 0; o < 20; ++o) {
        float t = b5[o];
        #pragma unroll
        for (int j = 0; j < 16; ++j) t = fmaf(h4[j], W5[j * 20 + o], t);
        o5[o] = t;
    }
    float4* outv = reinterpret_cast<float4*>(out + (size_t)s * 20);
    #pragma unroll
    for (int i = 0; i < 5; ++i)
        outv[i] = make_float4(o5[4 * i], o5[4 * i + 1], o5[4 * i + 2], o5[4 * i + 3]);
}

// ---------------------------------------------------------------------------
extern "C" void kernel_launch(void* const* d_in, const int* in_sizes, int n_in,
                              void* d_out, int out_size, void* d_ws, size_t ws_size,
                              hipStream_t stream) {
    const float* x  = (const float*)d_in[0];
    const float* W1 = (const float*)d_in[1];
    const float* b1 = (const float*)d_in[2];
    const float* W2 = (const float*)d_in[3];
    const float* b2 = (const float*)d_in[4];
    const float* W3 = (const float*)d_in[5];
    const float* b3 = (const float*)d_in[6];
    const float* qw = (const float*)d_in[7];
    const float* W4 = (const float*)d_in[8];
    const float* b4 = (const float*)d_in[9];
    const float* W5 = (const float*)d_in[10];
    const float* b5 = (const float*)d_in[11];
    float* out = (float*)d_out;
    float* UT  = (float*)d_ws;   // 64*64*2 floats = 32 KB

    const int B = in_sizes[0] / 128;

    build_u<<<64, 64, 0, stream>>>(qw, UT);
    fused_main<<<(B + 255) / 256, 256, 0, stream>>>(
        x, W1, b1, W2, b2, W3, b3, W4, b4, W5, b5, UT, out, B);
}

// Round 4
// 181.826 us; speedup vs baseline: 1.4302x; 1.2563x over previous
//
#include <hip/hip_runtime.h>
#include <hip/hip_bf16.h>
#include <math.h>

#define PI_F 3.14159265358979323846f

// ---------------------------------------------------------------------------
// Kernel 1: build the fixed 64x64 complex unitary U (everything after the
// input RY layer). One block per INPUT basis state b (64 blocks x 64 lanes).
// Lane l holds amplitude of flat index l. Qubit q <-> bit (5-q).
// Store ROW-major by output index k: U2[(k*64 + j)*2 + {0,1}] = {Re,Im} of
// U[k][j]. Row k = 512 contiguous bytes -> lane k loads its row as 32 float4.
// ---------------------------------------------------------------------------
__global__ __launch_bounds__(64) void build_u(const float* __restrict__ qw,
                                              float* __restrict__ U2) {
    const int l = threadIdx.x;   // amplitude index k (0..63)
    const int b = blockIdx.x;    // input basis state j (0..63)

    float ar = (l == b) ? 1.0f : 0.0f;
    float ai = 0.0f;

    // Phase 2: for i: RX(qw[0][i], i) ; RZ(qw[1][i], i)
    #pragma unroll
    for (int i = 0; i < 6; ++i) {
        const int mask = 1 << (5 - i);
        float th = 0.5f * qw[0 * 6 + i];
        float c = cosf(th), sn = sinf(th);
        float pr = __shfl_xor(ar, mask);
        float pi = __shfl_xor(ai, mask);
        float nr = c * ar + sn * pi;
        float ni = c * ai - sn * pr;
        ar = nr; ai = ni;
        th = 0.5f * qw[1 * 6 + i];
        c = cosf(th); sn = sinf(th);
        float zn = (l & mask) ? 1.0f : -1.0f;
        nr = c * ar - zn * sn * ai;
        ni = c * ai + zn * sn * ar;
        ar = nr; ai = ni;
    }

    // CNOT ring: (0,1),(1,2),(2,3),(3,4),(4,5),(5,0)
    #pragma unroll
    for (int i = 0; i < 6; ++i) {
        const int ctrl = i, tgt = (i + 1) % 6;
        const int cm = 1 << (5 - ctrl), tm = 1 << (5 - tgt);
        float pr = __shfl_xor(ar, tm);
        float pi = __shfl_xor(ai, tm);
        bool take = (l & cm) != 0;
        ar = take ? pr : ar;
        ai = take ? pi : ai;
    }

    // Phase 4: for i: RY(qw[2][i], i) ; RZ(qw[3][i], i)
    #pragma unroll
    for (int i = 0; i < 6; ++i) {
        const int mask = 1 << (5 - i);
        float th = 0.5f * qw[2 * 6 + i];
        float c = cosf(th), sn = sinf(th);
        float pr = __shfl_xor(ar, mask);
        float pi = __shfl_xor(ai, mask);
        float sg = (l & mask) ? sn : -sn;
        float nr = c * ar + sg * pr;
        float ni = c * ai + sg * pi;
        ar = nr; ai = ni;
        th = 0.5f * qw[3 * 6 + i];
        c = cosf(th); sn = sinf(th);
        float zn = (l & mask) ? 1.0f : -1.0f;
        nr = c * ar - zn * sn * ai;
        ni = c * ai + zn * sn * ar;
        ar = nr; ai = ni;
    }

    // CNOTs (0,1),(2,3),(4,5)
    #pragma unroll
    for (int i = 0; i < 6; i += 2) {
        const int cm = 1 << (5 - i), tm = 1 << (5 - (i + 1));
        float pr = __shfl_xor(ar, tm);
        float pi = __shfl_xor(ai, tm);
        bool take = (l & cm) != 0;
        ar = take ? pr : ar;
        ai = take ? pi : ai;
    }

    // Phase 6: RX(qw[4][i], i)
    #pragma unroll
    for (int i = 0; i < 6; ++i) {
        const int mask = 1 << (5 - i);
        float th = 0.5f * qw[4 * 6 + i];
        float c = cosf(th), sn = sinf(th);
        float pr = __shfl_xor(ar, mask);
        float pi = __shfl_xor(ai, mask);
        float nr = c * ar + sn * pi;
        float ni = c * ai - sn * pr;
        ar = nr; ai = ni;
    }

    U2[(l * 64 + b) * 2 + 0] = ar;   // row l (output k), col b (input j)
    U2[(l * 64 + b) * 2 + 1] = ai;
}

// uniform-lane readlane -> SGPR float
__device__ __forceinline__ float readlane_f(float v, int srclane) {
    return __int_as_float(__builtin_amdgcn_readlane(__float_as_int(v), srclane));
}

// ---------------------------------------------------------------------------
// Kernel 2: wave-cooperative fused pipeline. One WAVE owns 64 samples.
// Lane k holds U row k in 128 VGPRs (loaded once). Per sample t: broadcast
// lane t's hi/lo tables via readlane (SGPR operands), lane k computes
// phi_k (144 FMA, zero memory), p_k=|phi_k|^2, then a 6-stage Walsh-Hadamard
// shfl_xor butterfly yields the 6 signed sums; owner lane collects them.
// MLP front/back remain per-lane for the lane's own sample.
// ---------------------------------------------------------------------------
__global__ __launch_bounds__(256, 2) void fused_main(
    const float* __restrict__ x,
    const float* __restrict__ W1, const float* __restrict__ b1,
    const float* __restrict__ W2, const float* __restrict__ b2,
    const float* __restrict__ W3, const float* __restrict__ b3,
    const float* __restrict__ W4, const float* __restrict__ b4,
    const float* __restrict__ W5, const float* __restrict__ b5,
    const float* __restrict__ U2,
    float* __restrict__ out, int B)
{
    const int lane = threadIdx.x & 63;
    const int wv   = threadIdx.x >> 6;
    const long sbase = ((long)blockIdx.x * 4 + wv) * 64;
    const int  s_my  = (int)(sbase + lane);          // this lane's own sample
    const int  s_ld  = (s_my < B) ? s_my : (B - 1);  // clamped for loads

    // ---- Layer 1: h1 = relu(x[s,:] @ W1 + b1)   (128 -> 32)
    float h1[32];
    #pragma unroll
    for (int o = 0; o < 32; ++o) h1[o] = b1[o];
    const float4* x4 = reinterpret_cast<const float4*>(x + (size_t)s_ld * 128);
    #pragma unroll 1
    for (int j4 = 0; j4 < 32; ++j4) {
        float4 xv = x4[j4];
        const float* w = W1 + j4 * 4 * 32;   // row-major (128,32)
        #pragma unroll
        for (int o = 0; o < 32; ++o) h1[o] = fmaf(xv.x, w[o], h1[o]);
        #pragma unroll
        for (int o = 0; o < 32; ++o) h1[o] = fmaf(xv.y, w[32 + o], h1[o]);
        #pragma unroll
        for (int o = 0; o < 32; ++o) h1[o] = fmaf(xv.z, w[64 + o], h1[o]);
        #pragma unroll
        for (int o = 0; o < 32; ++o) h1[o] = fmaf(xv.w, w[96 + o], h1[o]);
    }
    #pragma unroll
    for (int o = 0; o < 32; ++o) h1[o] = fmaxf(h1[o], 0.0f);

    // ---- Layer 2: h2 = relu(h1 @ W2 + b2)   (32 -> 16)
    float h2[16];
    #pragma unroll
    for (int o = 0; o < 16; ++o) h2[o] = b2[o];
    #pragma unroll
    for (int j = 0; j < 32; ++j) {
        #pragma unroll
        for (int o = 0; o < 16; ++o) h2[o] = fmaf(h1[j], W2[j * 16 + o], h2[o]);
    }
    #pragma unroll
    for (int o = 0; o < 16; ++o) h2[o] = fmaxf(h2[o], 0.0f);

    // ---- Layer 3: angles -> half-angle cos/sin per qubit
    float cq[6], sq[6];
    #pragma unroll
    for (int q = 0; q < 6; ++q) {
        float t = b3[q];
        #pragma unroll
        for (int j = 0; j < 16; ++j) t = fmaf(h2[j], W3[j * 6 + q], t);
        t = tanhf(t);
        t = fminf(1.0f, fmaxf(-1.0f, t));
        float half = t * (0.5f * PI_F);
        sq[q] = sinf(half);
        cq[q] = cosf(half);
    }

    // ---- half-product tables: psi[j] = hi[j>>3] * lo[j&7]
    float lo[8], hi[8];
    {
        float f3[2] = {cq[3], sq[3]};
        float f4[2] = {cq[4], sq[4]};
        float f5[2] = {cq[5], sq[5]};
        #pragma unroll
        for (int m = 0; m < 8; ++m)
            lo[m] = f3[(m >> 2) & 1] * f4[(m >> 1) & 1] * f5[m & 1];
        float f0[2] = {cq[0], sq[0]};
        float f1[2] = {cq[1], sq[1]};
        float f2[2] = {cq[2], sq[2]};
        #pragma unroll
        for (int m = 0; m < 8; ++m)
            hi[m] = f0[(m >> 2) & 1] * f1[(m >> 1) & 1] * f2[m & 1];
    }

    // ---- load this lane's U row (output index k = lane): 32 float4 = 128 VGPR
    float4 u4[32];
    {
        const float4* urow = reinterpret_cast<const float4*>(U2 + lane * 128);
        #pragma unroll
        for (int t = 0; t < 32; ++t) u4[t] = urow[t];
    }

    // ---- cooperative sample loop
    float q0 = 0.f, q1 = 0.f, q2 = 0.f, q3 = 0.f, q4 = 0.f, q5 = 0.f;

    #pragma unroll 1
    for (int t = 0; t < 64; ++t) {
        // broadcast sample t's tables into SGPRs
        float bl0 = readlane_f(lo[0], t), bl1 = readlane_f(lo[1], t);
        float bl2 = readlane_f(lo[2], t), bl3 = readlane_f(lo[3], t);
        float bl4 = readlane_f(lo[4], t), bl5 = readlane_f(lo[5], t);
        float bl6 = readlane_f(lo[6], t), bl7 = readlane_f(lo[7], t);
        float bh0 = readlane_f(hi[0], t), bh1 = readlane_f(hi[1], t);
        float bh2 = readlane_f(hi[2], t), bh3 = readlane_f(hi[3], t);
        float bh4 = readlane_f(hi[4], t), bh5 = readlane_f(hi[5], t);
        float bh6 = readlane_f(hi[6], t), bh7 = readlane_f(hi[7], t);

        // phi_k = sum_jh bh[jh] * (sum_jl U[k][8jh+jl] * bl[jl])
        float pr = 0.f, pim = 0.f;
        #pragma unroll
        for (int jh = 0; jh < 8; ++jh) {
            float tr = 0.f, ti = 0.f;
            // j = jh*8 + jl ; u4[j>>1]: even j -> (x=re, y=im), odd j -> (z=re, w=im)
            #pragma unroll
            for (int jl = 0; jl < 8; ++jl) {
                const int j = jh * 8 + jl;
                const float ure = (j & 1) ? u4[j >> 1].z : u4[j >> 1].x;
                const float uim = (j & 1) ? u4[j >> 1].w : u4[j >> 1].y;
                const float blv = (jl == 0) ? bl0 : (jl == 1) ? bl1 : (jl == 2) ? bl2 :
                                  (jl == 3) ? bl3 : (jl == 4) ? bl4 : (jl == 5) ? bl5 :
                                  (jl == 6) ? bl6 : bl7;
                tr = fmaf(ure, blv, tr);
                ti = fmaf(uim, blv, ti);
            }
            const float bhv = (jh == 0) ? bh0 : (jh == 1) ? bh1 : (jh == 2) ? bh2 :
                              (jh == 3) ? bh3 : (jh == 4) ? bh4 : (jh == 5) ? bh5 :
                              (jh == 6) ? bh6 : bh7;
            pr  = fmaf(bhv, tr, pr);
            pim = fmaf(bhv, ti, pim);
        }
        float p = fmaf(pr, pr, pim * pim);   // |phi_k|^2 at lane k

        // Walsh-Hadamard butterfly: lane r ends with sum_k (-1)^{popc(r&k)} p_k
        float v = p;
        #pragma unroll
        for (int st = 0; st < 6; ++st) {
            const int m = 1 << st;
            float prt = __shfl_xor(v, m);
            v = (lane & m) ? (prt - v) : (prt + v);
        }

        // qv[q] = WHT coefficient at r = 1<<(5-q); deliver to owner lane t
        float g0 = readlane_f(v, 32);
        float g1 = readlane_f(v, 16);
        float g2 = readlane_f(v, 8);
        float g3 = readlane_f(v, 4);
        float g4 = readlane_f(v, 2);
        float g5 = readlane_f(v, 1);
        if (lane == t) { q0 = g0; q1 = g1; q2 = g2; q3 = g3; q4 = g4; q5 = g5; }
    }

    if (s_my >= B) return;

    // ---- Layer 4: h4 = relu(q_out @ W4 + b4)   (6 -> 16)
    float qv[6] = {q0, q1, q2, q3, q4, q5};
    float h4[16];
    #pragma unroll
    for (int o = 0; o < 16; ++o) h4[o] = b4[o];
    #pragma unroll
    for (int q = 0; q < 6; ++q) {
        #pragma unroll
        for (int o = 0; o < 16; ++o) h4[o] = fmaf(qv[q], W4[q * 16 + o], h4[o]);
    }
    #pragma unroll
    for (int o = 0; o < 16; ++o) h4[o] = fmaxf(h4[o], 0.0f);

    // ---- Layer 5: out = h4 @ W5 + b5   (16 -> 20)
    float o5[20];
    #pragma unroll
    for (int o = 0; o < 20; ++o) {
        float t = b5[o];
        #pragma unroll
        for (int j = 0; j < 16; ++j) t = fmaf(h4[j], W5[j * 20 + o], t);
        o5[o] = t;
    }
    float4* outv = reinterpret_cast<float4*>(out + (size_t)s_my * 20);
    #pragma unroll
    for (int i = 0; i < 5; ++i)
        outv[i] = make_float4(o5[4 * i], o5[4 * i + 1], o5[4 * i + 2], o5[4 * i + 3]);
}

// ---------------------------------------------------------------------------
extern "C" void kernel_launch(void* const* d_in, const int* in_sizes, int n_in,
                              void* d_out, int out_size, void* d_ws, size_t ws_size,
                              hipStream_t stream) {
    const float* x  = (const float*)d_in[0];
    const float* W1 = (const float*)d_in[1];
    const float* b1 = (const float*)d_in[2];
    const float* W2 = (const float*)d_in[3];
    const float* b2 = (const float*)d_in[4];
    const float* W3 = (const float*)d_in[5];
    const float* b3 = (const float*)d_in[6];
    const float* qw = (const float*)d_in[7];
    const float* W4 = (const float*)d_in[8];
    const float* b4 = (const float*)d_in[9];
    const float* W5 = (const float*)d_in[10];
    const float* b5 = (const float*)d_in[11];
    float* out = (float*)d_out;
    float* U2  = (float*)d_ws;   // 64*64*2 floats = 32 KB

    const int B = in_sizes[0] / 128;

    build_u<<<64, 64, 0, stream>>>(qw, U2);
    fused_main<<<(B + 255) / 256, 256, 0, stream>>>(
        x, W1, b1, W2, b2, W3, b3, W4, b4, W5, b5, U2, out, B);
}